// Round 2
// 641.167 us; speedup vs baseline: 1.0733x; 1.0733x over previous
//
#include <hip/hip_runtime.h>
#include <hip/hip_fp16.h>
#include <cstddef>

#define NN    100000
#define EE    1600000
#define F1D   512
#define F3D   128
#define HD    128
#define CD    64
#define SWc   0.2f
#define FWc   0.8f
#define BN_EPS 1e-5f

#define SCAN_B 1024
#define NB ((NN + SCAN_B - 1) / SCAN_B)   // 98

// Bucketed CSR build params
#define BSH   7                            // bucket = dst >> 7 (128 nodes/bucket)
#define NBKA  1024                         // bucket array size (782 used)
#define NBUK  ((NN + 127) / 128)           // 782
#define CHK   4096                         // edges per multi-split chunk
#define BCAP  8192                         // LDS staging capacity per bucket

typedef _Float16 half8 __attribute__((ext_vector_type(8)));
typedef float f32x4 __attribute__((ext_vector_type(4)));

// ===========================================================================
// CSR build: deg-count -> 3-phase multi-block scan -> bucketed placement
// ===========================================================================
__global__ __launch_bounds__(256) void count_kernel(
    const int* __restrict__ dst, int* __restrict__ deg)
{
    int e = blockIdx.x * 256 + threadIdx.x;
    if (e < EE) atomicAdd(&deg[dst[e]], 1);
}

// Phase A: per-block reduce of deg -> partials[NB]
__global__ __launch_bounds__(SCAN_B) void scan_partial_kernel(
    const int* __restrict__ deg, int* __restrict__ partials)
{
    __shared__ int sh[SCAN_B / 64];
    int i = blockIdx.x * SCAN_B + threadIdx.x;
    int v = (i < NN) ? deg[i] : 0;
#pragma unroll
    for (int d = 32; d > 0; d >>= 1) v += __shfl_down(v, d, 64);
    int lane = threadIdx.x & 63, wv = threadIdx.x >> 6;
    if (lane == 0) sh[wv] = v;
    __syncthreads();
    if (threadIdx.x < SCAN_B / 64) {
        int s = sh[threadIdx.x];
#pragma unroll
        for (int d = SCAN_B / 128; d > 0; d >>= 1) s += __shfl_down(s, d, 64);
        if (threadIdx.x == 0) partials[blockIdx.x] = s;
    }
}

// Phase B: 1 small block exclusive-scans partials in place; writes offsets[NN]
__global__ __launch_bounds__(128) void scan_base_kernel(
    int* __restrict__ partials, int* __restrict__ offsets)
{
    __shared__ int sh[128];
    int t = threadIdx.x;
    int v = (t < NB) ? partials[t] : 0;
    sh[t] = v;
    __syncthreads();
    for (int d = 1; d < 128; d <<= 1) {
        int u = (t >= d) ? sh[t - d] : 0;
        __syncthreads();
        sh[t] += u;
        __syncthreads();
    }
    if (t < NB) partials[t] = sh[t] - v;           // exclusive base per block
    if (t == NB - 1) offsets[NN] = sh[t];          // total == EE
}

// Phase C: per-block Hillis-Steele scan + base -> offsets & cursor
__global__ __launch_bounds__(SCAN_B) void scan_apply_kernel(
    const int* __restrict__ deg, const int* __restrict__ partials,
    int* __restrict__ offsets, int* __restrict__ cursor)
{
    __shared__ int sh[SCAN_B];
    int t = threadIdx.x;
    int i = blockIdx.x * SCAN_B + t;
    int v = (i < NN) ? deg[i] : 0;
    sh[t] = v;
    __syncthreads();
    for (int d = 1; d < SCAN_B; d <<= 1) {
        int u = (t >= d) ? sh[t - d] : 0;
        __syncthreads();
        sh[t] += u;
        __syncthreads();
    }
    if (i < NN) {
        int excl = sh[t] - v + partials[blockIdx.x];
        offsets[i] = excl;
        cursor[i]  = excl;
    }
}

// Init bucket cursors: gcur[b] = offsets[min(b*128, NN)]
__global__ __launch_bounds__(256) void binit_kernel(
    const int* __restrict__ offsets, int* __restrict__ gcur)
{
    int b = blockIdx.x * 256 + threadIdx.x;
    if (b < NBKA) {
        int n = b << BSH;
        if (n > NN) n = NN;
        gcur[b] = offsets[n];
    }
}

// Multi-split: chunk -> LDS histogram by bucket -> scan -> global reserve ->
// LDS reorder -> coalesced run writes into ebuf. ebuf region for bucket b is
// exactly [offsets[b*128], offsets[(b+1)*128]) since gcur starts there and
// total per-bucket count == sum of degs in its node range.
__global__ __launch_bounds__(256) void bucket_kernel(
    const int* __restrict__ src, const int* __restrict__ dst,
    int* __restrict__ gcur, int* __restrict__ ebuf)
{
    __shared__ int hist[NBKA];     // counts -> exclusive offsets -> cursor
    __shared__ int gb2[NBKA];      // global_base - local_offset
    __shared__ int tsum[256];
    __shared__ int stage[CHK];     // packed (src<<7)|dlocal, bucket-ordered
    __shared__ int destg[CHK];     // global destination index in ebuf

    const int t  = threadIdx.x;
    const int e0 = blockIdx.x * CHK;
    int ecnt = EE - e0;
    if (ecnt > CHK) ecnt = CHK;

    for (int b = t; b < NBKA; b += 256) hist[b] = 0;
    __syncthreads();

    // pass 1: histogram
    for (int i = t; i < ecnt; i += 256) {
        int d = dst[e0 + i];
        atomicAdd(&hist[d >> BSH], 1);
    }
    __syncthreads();

    // exclusive scan of 1024 counts (thread t owns buckets 4t..4t+3)
    int a0 = hist[4 * t], a1 = hist[4 * t + 1];
    int a2 = hist[4 * t + 2], a3 = hist[4 * t + 3];
    int tot = a0 + a1 + a2 + a3;
    tsum[t] = tot;
    __syncthreads();
    for (int d = 1; d < 256; d <<= 1) {
        int u = (t >= d) ? tsum[t - d] : 0;
        __syncthreads();
        tsum[t] += u;
        __syncthreads();
    }
    int base = tsum[t] - tot;
    int o0 = base, o1 = base + a0, o2 = base + a0 + a1, o3 = base + a0 + a1 + a2;
    // reserve global runs (one atomic per non-empty (block,bucket))
    if (a0 > 0) gb2[4 * t]     = atomicAdd(&gcur[4 * t],     a0) - o0;
    if (a1 > 0) gb2[4 * t + 1] = atomicAdd(&gcur[4 * t + 1], a1) - o1;
    if (a2 > 0) gb2[4 * t + 2] = atomicAdd(&gcur[4 * t + 2], a2) - o2;
    if (a3 > 0) gb2[4 * t + 3] = atomicAdd(&gcur[4 * t + 3], a3) - o3;
    hist[4 * t] = o0; hist[4 * t + 1] = o1;
    hist[4 * t + 2] = o2; hist[4 * t + 3] = o3;
    __syncthreads();

    // pass 2: re-read edges, place into LDS staging ordered by bucket
    for (int i = t; i < ecnt; i += 256) {
        int d = dst[e0 + i];
        int s = src[e0 + i];
        int b = d >> BSH;
        int pos = atomicAdd(&hist[b], 1);
        stage[pos] = (s << BSH) | (d & 127);
        destg[pos] = gb2[b] + pos;
    }
    __syncthreads();

    // pass 3: coalesced copy-out (consecutive slots -> consecutive dest in runs)
    for (int sx = t; sx < ecnt; sx += 256) ebuf[destg[sx]] = stage[sx];
}

// Per-bucket placement: scatter inside LDS via per-node cursors, then one
// contiguous coalesced dump into csr. Fallback to global-cursor scatter for
// (practically nonexistent) buckets larger than BCAP.
__global__ __launch_bounds__(256) void csr_place_kernel(
    const int* __restrict__ ebuf, const int* __restrict__ offsets,
    int* __restrict__ cursor, int* __restrict__ csr)
{
    __shared__ int lcur[128];
    __shared__ int stage[BCAP];

    const int b   = blockIdx.x;
    const int t   = threadIdx.x;
    const int nb0 = b << BSH;
    int nb1 = nb0 + 128;
    if (nb1 > NN) nb1 = NN;
    const int rbeg = offsets[nb0];
    const int rend = offsets[nb1];
    const int L = rend - rbeg;

    if (L <= BCAP) {
        if (t < nb1 - nb0) lcur[t] = offsets[nb0 + t] - rbeg;
        __syncthreads();
        for (int e = rbeg + t; e < rend; e += 256) {
            int p = ebuf[e];
            int pos = atomicAdd(&lcur[p & 127], 1);
            stage[pos] = p >> BSH;
        }
        __syncthreads();
        for (int s = t; s < L; s += 256) csr[rbeg + s] = stage[s];
    } else {
        for (int e = rbeg + t; e < rend; e += 256) {
            int p = ebuf[e];
            int node = nb0 + (p & 127);
            int pos = atomicAdd(&cursor[node], 1);
            csr[pos] = p >> BSH;
        }
    }
}

// ===========================================================================
// Prep: Wc_t[n=128][k=640] = f16(FW*W1^T | SW*W2^T); Wg1_t[n=128][k=128];
//       Wg2_t[n=64][k=128]; hbuf[128] = FW*b1 + SW*b2
// ===========================================================================
__global__ __launch_bounds__(256) void prep_kernel(
    const float* __restrict__ W1, const float* __restrict__ W2,
    const float* __restrict__ Wg1, const float* __restrict__ Wg2,
    const float* __restrict__ b1, const float* __restrict__ b2,
    _Float16* __restrict__ Wc_t, _Float16* __restrict__ Wg1_t,
    _Float16* __restrict__ Wg2_t, float* __restrict__ hbuf)
{
    int i = blockIdx.x * 256 + threadIdx.x;
    if (i < 128 * 640) {
        int n = i / 640, k = i % 640;
        float v = (k < F1D) ? FWc * W1[(size_t)k * HD + n]
                            : SWc * W2[(size_t)(k - F1D) * HD + n];
        Wc_t[i] = (_Float16)v;
    } else if (i < 128 * 640 + 128 * 128) {
        int j = i - 128 * 640; int n = j / 128, k = j % 128;
        Wg1_t[j] = (_Float16)Wg1[(size_t)k * HD + n];
    } else if (i < 128 * 640 + 128 * 128 + 64 * 128) {
        int j = i - 128 * 640 - 128 * 128; int n = j / 128, k = j % 128;
        Wg2_t[j] = (_Float16)Wg2[(size_t)k * CD + n];
    } else if (i < 128 * 640 + 128 * 128 + 64 * 128 + 128) {
        int j = i - (128 * 640 + 128 * 128 + 64 * 128);
        hbuf[j] = FWc * b1[j] + SWc * b2[j];
    }
}

// ===========================================================================
// GEMM1 (MFMA f16): h = [x1|x2] @ Wc + hb;  z = h @ Wg1   (z f16)
// Block 256 = 4 waves. Tile M=128, N=128, K=640 (BK=64). Wave: 32 rows x 128.
// ===========================================================================
__global__ __launch_bounds__(256) void gemm1_mfma(
    const float* __restrict__ x1, const float* __restrict__ x2,
    const _Float16* __restrict__ Wc_t, const _Float16* __restrict__ Wg1_t,
    const float* __restrict__ hbuf, _Float16* __restrict__ z)
{
    __shared__ __align__(16) _Float16 As[128][72];
    __shared__ __align__(16) _Float16 Bs[128][72];
    __shared__ __align__(16) _Float16 Hs[128][136];

    const int tid  = threadIdx.x;
    const int wave = tid >> 6;
    const int lane = tid & 63;
    const int quad = lane >> 4;
    const int l16  = lane & 15;
    const int row0 = blockIdx.x * 128;

    const int sr = tid >> 1;           // staging row 0..127
    const int sc = (tid & 1) * 32;     // staging col offset

    f32x4 acc[2][8];
    const f32x4 zero4 = {0.f, 0.f, 0.f, 0.f};
#pragma unroll
    for (int mi = 0; mi < 2; ++mi)
#pragma unroll
        for (int ni = 0; ni < 8; ++ni) acc[mi][ni] = zero4;

    // ---- Phase 1: h = X @ Wc over K=640 in 10 tiles of 64 ----
    for (int t = 0; t < 10; ++t) {
        const float* xp; int stride, kb;
        if (t < 8) { xp = x1; stride = F1D; kb = t * 64; }
        else       { xp = x2; stride = F3D; kb = (t - 8) * 64; }
        __syncthreads();
        {
            int gr = row0 + sr;
            if (gr < NN) {
                const float4* rp = (const float4*)(xp + (size_t)gr * stride + kb + sc);
#pragma unroll
                for (int i = 0; i < 4; ++i) {
                    float4 f0 = rp[2 * i];
                    float4 f1 = rp[2 * i + 1];
                    half8 hv = { (_Float16)f0.x, (_Float16)f0.y, (_Float16)f0.z, (_Float16)f0.w,
                                 (_Float16)f1.x, (_Float16)f1.y, (_Float16)f1.z, (_Float16)f1.w };
                    *(half8*)&As[sr][sc + i * 8] = hv;
                }
            } else {
                half8 zv = { (_Float16)0.f, (_Float16)0.f, (_Float16)0.f, (_Float16)0.f,
                             (_Float16)0.f, (_Float16)0.f, (_Float16)0.f, (_Float16)0.f };
#pragma unroll
                for (int i = 0; i < 4; ++i) *(half8*)&As[sr][sc + i * 8] = zv;
            }
            const _Float16* wp = Wc_t + (size_t)sr * 640 + t * 64 + sc;
#pragma unroll
            for (int i = 0; i < 4; ++i)
                *(half8*)&Bs[sr][sc + i * 8] = *(const half8*)(wp + i * 8);
        }
        __syncthreads();
#pragma unroll
        for (int ks = 0; ks < 2; ++ks) {
            half8 a[2], b[8];
#pragma unroll
            for (int mi = 0; mi < 2; ++mi)
                a[mi] = *(const half8*)&As[wave * 32 + mi * 16 + l16][ks * 32 + quad * 8];
#pragma unroll
            for (int ni = 0; ni < 8; ++ni)
                b[ni] = *(const half8*)&Bs[ni * 16 + l16][ks * 32 + quad * 8];
#pragma unroll
            for (int mi = 0; mi < 2; ++mi)
#pragma unroll
                for (int ni = 0; ni < 8; ++ni)
                    acc[mi][ni] = __builtin_amdgcn_mfma_f32_16x16x32_f16(
                        a[mi], b[ni], acc[mi][ni], 0, 0, 0);
        }
    }

    // ---- h + bias -> Hs (f16). C-layout: col=l16, row=quad*4+r. ----
    {
        float hbv[8];
#pragma unroll
        for (int ni = 0; ni < 8; ++ni) hbv[ni] = hbuf[ni * 16 + l16];
#pragma unroll
        for (int mi = 0; mi < 2; ++mi)
#pragma unroll
            for (int ni = 0; ni < 8; ++ni)
#pragma unroll
                for (int r = 0; r < 4; ++r)
                    Hs[wave * 32 + mi * 16 + quad * 4 + r][ni * 16 + l16] =
                        (_Float16)(acc[mi][ni][r] + hbv[ni]);
    }

    // ---- Phase 2: z = h @ Wg1, K=128 in 2 tiles of 64 (Bs reused) ----
#pragma unroll
    for (int mi = 0; mi < 2; ++mi)
#pragma unroll
        for (int ni = 0; ni < 8; ++ni) acc[mi][ni] = zero4;

    for (int t = 0; t < 2; ++t) {
        __syncthreads();
        {
            const _Float16* wp = Wg1_t + (size_t)sr * 128 + t * 64 + sc;
#pragma unroll
            for (int i = 0; i < 4; ++i)
                *(half8*)&Bs[sr][sc + i * 8] = *(const half8*)(wp + i * 8);
        }
        __syncthreads();
#pragma unroll
        for (int ks = 0; ks < 2; ++ks) {
            half8 a[2], b[8];
#pragma unroll
            for (int mi = 0; mi < 2; ++mi)
                a[mi] = *(const half8*)&Hs[wave * 32 + mi * 16 + l16][t * 64 + ks * 32 + quad * 8];
#pragma unroll
            for (int ni = 0; ni < 8; ++ni)
                b[ni] = *(const half8*)&Bs[ni * 16 + l16][ks * 32 + quad * 8];
#pragma unroll
            for (int mi = 0; mi < 2; ++mi)
#pragma unroll
                for (int ni = 0; ni < 8; ++ni)
                    acc[mi][ni] = __builtin_amdgcn_mfma_f32_16x16x32_f16(
                        a[mi], b[ni], acc[mi][ni], 0, 0, 0);
        }
    }

    // ---- z tile -> Hs (overwrite, wave-own rows), then coalesced store ----
#pragma unroll
    for (int mi = 0; mi < 2; ++mi)
#pragma unroll
        for (int ni = 0; ni < 8; ++ni)
#pragma unroll
            for (int r = 0; r < 4; ++r)
                Hs[wave * 32 + mi * 16 + quad * 4 + r][ni * 16 + l16] =
                    (_Float16)acc[mi][ni][r];
    __syncthreads();
    {
        int gr = row0 + sr;
        if (gr < NN) {
            int c0 = (tid & 1) * 64;
            _Float16* zp = z + (size_t)gr * HD + c0;
#pragma unroll
            for (int i = 0; i < 8; ++i)
                *(half8*)(zp + i * 8) = *(const half8*)&Hs[sr][c0 + i * 8];
        }
    }
}

// ===========================================================================
// GEMM2 (MFMA f16, fused BN+ReLU): z2 = relu(agg*s + t) @ Wg2   (z2 f16)
// ===========================================================================
__global__ __launch_bounds__(256) void gemm2_mfma(
    const float* __restrict__ agg, const _Float16* __restrict__ Wg2_t,
    const float* __restrict__ bg1, const float* __restrict__ gamma,
    const float* __restrict__ beta, const float* __restrict__ rmean,
    const float* __restrict__ rvar, _Float16* __restrict__ z2)
{
    __shared__ __align__(16) _Float16 As[128][72];
    __shared__ __align__(16) _Float16 Bs[64][72];
    __shared__ float sS[HD], sT[HD];

    const int tid = threadIdx.x;
    if (tid < HD) {
        float s = gamma[tid] * rsqrtf(rvar[tid] + BN_EPS);
        sS[tid] = s;
        sT[tid] = (bg1[tid] - rmean[tid]) * s + beta[tid];
    }
    __syncthreads();

    const int wave = tid >> 6;
    const int lane = tid & 63;
    const int quad = lane >> 4;
    const int l16  = lane & 15;
    const int row0 = blockIdx.x * 128;
    const int sr = tid >> 1;
    const int sc = (tid & 1) * 32;

    f32x4 acc[2][4];
    const f32x4 zero4 = {0.f, 0.f, 0.f, 0.f};
#pragma unroll
    for (int mi = 0; mi < 2; ++mi)
#pragma unroll
        for (int ni = 0; ni < 4; ++ni) acc[mi][ni] = zero4;

    for (int t = 0; t < 2; ++t) {
        __syncthreads();
        {
            int gr = row0 + sr;
            if (gr < NN) {
                const float4* rp = (const float4*)(agg + (size_t)gr * HD + t * 64 + sc);
#pragma unroll
                for (int i = 0; i < 4; ++i) {
                    float4 f0 = rp[2 * i];
                    float4 f1 = rp[2 * i + 1];
                    int k = t * 64 + sc + i * 8;
                    float v0 = fmaxf(fmaf(f0.x, sS[k + 0], sT[k + 0]), 0.f);
                    float v1 = fmaxf(fmaf(f0.y, sS[k + 1], sT[k + 1]), 0.f);
                    float v2 = fmaxf(fmaf(f0.z, sS[k + 2], sT[k + 2]), 0.f);
                    float v3 = fmaxf(fmaf(f0.w, sS[k + 3], sT[k + 3]), 0.f);
                    float v4 = fmaxf(fmaf(f1.x, sS[k + 4], sT[k + 4]), 0.f);
                    float v5 = fmaxf(fmaf(f1.y, sS[k + 5], sT[k + 5]), 0.f);
                    float v6 = fmaxf(fmaf(f1.z, sS[k + 6], sT[k + 6]), 0.f);
                    float v7 = fmaxf(fmaf(f1.w, sS[k + 7], sT[k + 7]), 0.f);
                    half8 hv = { (_Float16)v0, (_Float16)v1, (_Float16)v2, (_Float16)v3,
                                 (_Float16)v4, (_Float16)v5, (_Float16)v6, (_Float16)v7 };
                    *(half8*)&As[sr][sc + i * 8] = hv;
                }
            } else {
                half8 zv = { (_Float16)0.f, (_Float16)0.f, (_Float16)0.f, (_Float16)0.f,
                             (_Float16)0.f, (_Float16)0.f, (_Float16)0.f, (_Float16)0.f };
#pragma unroll
                for (int i = 0; i < 4; ++i) *(half8*)&As[sr][sc + i * 8] = zv;
            }
            int n = tid >> 2, c = (tid & 3) * 16;
            const _Float16* wp = Wg2_t + (size_t)n * 128 + t * 64 + c;
            *(half8*)&Bs[n][c]     = *(const half8*)wp;
            *(half8*)&Bs[n][c + 8] = *(const half8*)(wp + 8);
        }
        __syncthreads();
#pragma unroll
        for (int ks = 0; ks < 2; ++ks) {
            half8 a[2], b[4];
#pragma unroll
            for (int mi = 0; mi < 2; ++mi)
                a[mi] = *(const half8*)&As[wave * 32 + mi * 16 + l16][ks * 32 + quad * 8];
#pragma unroll
            for (int ni = 0; ni < 4; ++ni)
                b[ni] = *(const half8*)&Bs[ni * 16 + l16][ks * 32 + quad * 8];
#pragma unroll
            for (int mi = 0; mi < 2; ++mi)
#pragma unroll
                for (int ni = 0; ni < 4; ++ni)
                    acc[mi][ni] = __builtin_amdgcn_mfma_f32_16x16x32_f16(
                        a[mi], b[ni], acc[mi][ni], 0, 0, 0);
        }
    }

    __syncthreads();
    // z2 tile -> As reuse (wave-own rows), then coalesced store
#pragma unroll
    for (int mi = 0; mi < 2; ++mi)
#pragma unroll
        for (int ni = 0; ni < 4; ++ni)
#pragma unroll
            for (int r = 0; r < 4; ++r)
                As[wave * 32 + mi * 16 + quad * 4 + r][ni * 16 + l16] =
                    (_Float16)acc[mi][ni][r];
    __syncthreads();
    {
        int gr = row0 + sr;
        if (gr < NN) {
            _Float16* zp = z2 + (size_t)gr * CD + sc;
            *(half8*)(zp)      = *(const half8*)&As[sr][sc];
            *(half8*)(zp + 8)  = *(const half8*)&As[sr][sc + 8];
            *(half8*)(zp + 16) = *(const half8*)&As[sr][sc + 16];
            *(half8*)(zp + 24) = *(const half8*)&As[sr][sc + 24];
        }
    }
}

// ===========================================================================
// Gather 1: agg[n] = sum_{e in CSR[n]} z[src[e]]  — 1 wave/node, 4 edges per
// load instruction (h = lane>>4 edge slot, fl = lane&15 -> 16B feature slice),
// 64 indices prefetched per chunk, #pragma unroll 4 => up to 16 edges in
// flight per wave.
// ===========================================================================
__global__ __launch_bounds__(256) void gather1_kernel(
    const _Float16* __restrict__ z, const int* __restrict__ offsets,
    const int* __restrict__ csr_src, float* __restrict__ agg)
{
    int node = blockIdx.x * 4 + (threadIdx.x >> 6);
    if (node >= NN) return;
    const int lane = threadIdx.x & 63;
    const int h  = lane >> 4;      // edge slot within quad
    const int fl = lane & 15;      // halves fl*8 .. fl*8+7 (16 B)

    int beg = offsets[node];
    int cnt = offsets[node + 1] - beg;

    float a0 = 0.f, a1 = 0.f, a2 = 0.f, a3 = 0.f;
    float a4 = 0.f, a5 = 0.f, a6 = 0.f, a7 = 0.f;

    for (int j0 = 0; j0 < cnt; j0 += 64) {
        int cntc = cnt - j0; if (cntc > 64) cntc = 64;
        int myidx = (lane < cntc) ? csr_src[beg + j0 + lane] : 0;
        int nq = (cntc + 3) >> 2;
#pragma unroll 4
        for (int i = 0; i < nq; ++i) {
            int e = i * 4 + h;
            int si = __shfl(myidx, e);
            float m = (e < cntc) ? 1.f : 0.f;
            float4 raw = *(const float4*)(z + (size_t)si * HD + fl * 8);
            const __half2* hp = (const __half2*)&raw;
            float2 f0 = __half22float2(hp[0]);
            float2 f1 = __half22float2(hp[1]);
            float2 f2 = __half22float2(hp[2]);
            float2 f3 = __half22float2(hp[3]);
            a0 = fmaf(m, f0.x, a0); a1 = fmaf(m, f0.y, a1);
            a2 = fmaf(m, f1.x, a2); a3 = fmaf(m, f1.y, a3);
            a4 = fmaf(m, f2.x, a4); a5 = fmaf(m, f2.y, a5);
            a6 = fmaf(m, f3.x, a6); a7 = fmaf(m, f3.y, a7);
        }
    }

    // reduce the 4 edge slots (lanes l, l^16, l^32, l^48)
    a0 += __shfl_xor(a0, 16); a1 += __shfl_xor(a1, 16);
    a2 += __shfl_xor(a2, 16); a3 += __shfl_xor(a3, 16);
    a4 += __shfl_xor(a4, 16); a5 += __shfl_xor(a5, 16);
    a6 += __shfl_xor(a6, 16); a7 += __shfl_xor(a7, 16);
    a0 += __shfl_xor(a0, 32); a1 += __shfl_xor(a1, 32);
    a2 += __shfl_xor(a2, 32); a3 += __shfl_xor(a3, 32);
    a4 += __shfl_xor(a4, 32); a5 += __shfl_xor(a5, 32);
    a6 += __shfl_xor(a6, 32); a7 += __shfl_xor(a7, 32);

    if (h == 0) {
        float* op = agg + (size_t)node * HD + fl * 8;
        float4 o0 = make_float4(a0, a1, a2, a3);
        float4 o1 = make_float4(a4, a5, a6, a7);
        *(float4*)op       = o0;
        *(float4*)(op + 4) = o1;
    }
}

// ===========================================================================
// Gather 2: out[n] = bg2 + sum_{e in CSR[n]} z2[src[e]] — same structure,
// 8 B feature slice per lane (row = 64 halves).
// ===========================================================================
__global__ __launch_bounds__(256) void gather2_kernel(
    const _Float16* __restrict__ z2, const int* __restrict__ offsets,
    const int* __restrict__ csr_src, const float* __restrict__ bg2,
    float* __restrict__ out)
{
    int node = blockIdx.x * 4 + (threadIdx.x >> 6);
    if (node >= NN) return;
    const int lane = threadIdx.x & 63;
    const int h  = lane >> 4;      // edge slot within quad
    const int fl = lane & 15;      // halves fl*4 .. fl*4+3 (8 B)

    int beg = offsets[node];
    int cnt = offsets[node + 1] - beg;

    float a0 = 0.f, a1 = 0.f, a2 = 0.f, a3 = 0.f;

    for (int j0 = 0; j0 < cnt; j0 += 64) {
        int cntc = cnt - j0; if (cntc > 64) cntc = 64;
        int myidx = (lane < cntc) ? csr_src[beg + j0 + lane] : 0;
        int nq = (cntc + 3) >> 2;
#pragma unroll 4
        for (int i = 0; i < nq; ++i) {
            int e = i * 4 + h;
            int si = __shfl(myidx, e);
            float m = (e < cntc) ? 1.f : 0.f;
            float2 raw = *(const float2*)(z2 + (size_t)si * CD + fl * 4);
            const __half2* hp = (const __half2*)&raw;
            float2 f0 = __half22float2(hp[0]);
            float2 f1 = __half22float2(hp[1]);
            a0 = fmaf(m, f0.x, a0); a1 = fmaf(m, f0.y, a1);
            a2 = fmaf(m, f1.x, a2); a3 = fmaf(m, f1.y, a3);
        }
    }

    a0 += __shfl_xor(a0, 16); a1 += __shfl_xor(a1, 16);
    a2 += __shfl_xor(a2, 16); a3 += __shfl_xor(a3, 16);
    a0 += __shfl_xor(a0, 32); a1 += __shfl_xor(a1, 32);
    a2 += __shfl_xor(a2, 32); a3 += __shfl_xor(a3, 32);

    if (h == 0) {
        float4 bv = *(const float4*)(bg2 + fl * 4);
        float4 o = make_float4(a0 + bv.x, a1 + bv.y, a2 + bv.z, a3 + bv.w);
        *(float4*)(out + (size_t)node * CD + fl * 4) = o;
    }
}

// ===========================================================================
extern "C" void kernel_launch(void* const* d_in, const int* in_sizes, int n_in,
                              void* d_out, int out_size, void* d_ws, size_t ws_size,
                              hipStream_t stream)
{
    const float* x1    = (const float*)d_in[0];
    const float* x2    = (const float*)d_in[1];
    const int*   ei    = (const int*)d_in[2];
    const float* W1    = (const float*)d_in[3];
    const float* b1    = (const float*)d_in[4];
    const float* W2    = (const float*)d_in[5];
    const float* b2    = (const float*)d_in[6];
    const float* Wg1   = (const float*)d_in[7];
    const float* bg1   = (const float*)d_in[8];
    const float* Wg2   = (const float*)d_in[9];
    const float* bg2   = (const float*)d_in[10];
    const float* gamma = (const float*)d_in[11];
    const float* beta  = (const float*)d_in[12];
    const float* rmean = (const float*)d_in[13];
    const float* rvar  = (const float*)d_in[14];
    float* out = (float*)d_out;

    // ---- workspace layout (all chunks 16B-aligned), ~85 MB ----
    char* p = (char*)d_ws;
    _Float16* z_h  = (_Float16*)p; p += (size_t)NN * HD * sizeof(_Float16);   // 25.6 MB
    float*  agg    = (float*)p;    p += (size_t)NN * HD * sizeof(float);      // 51.2 MB
    int*    csr    = (int*)p;      p += (size_t)EE * sizeof(int);             // 6.4 MB
    int*    offs   = (int*)p;      p += (size_t)(NN + 16) * sizeof(int);
    int*    curs   = (int*)p;      p += (size_t)(NN + 16) * sizeof(int);
    int*    deg    = (int*)p;      p += (size_t)(NN + 16) * sizeof(int);
    int*    parts  = (int*)p;      p += (size_t)(NB + 16) * sizeof(int);
    int*    gcur   = (int*)p;      p += (size_t)(NBKA + 16) * sizeof(int);    // 4 KB
    _Float16* Wc_t = (_Float16*)p; p += (size_t)128 * 640 * sizeof(_Float16); // 160 KB
    _Float16* Wg1t = (_Float16*)p; p += (size_t)128 * 128 * sizeof(_Float16);
    _Float16* Wg2t = (_Float16*)p; p += (size_t)64 * 128 * sizeof(_Float16);
    float*  hbuf   = (float*)p;    p += 128 * sizeof(float);
    _Float16* z2_h = z_h;          // overlay: z dead after gather1
    int*    ebuf   = (int*)agg;    // overlay: agg written only after csr_place

    const int* src = ei;
    const int* dst = ei + EE;

    // Weight prep (f16, transposed, scales folded)
    prep_kernel<<<(128 * 640 + 128 * 128 + 64 * 128 + 128 + 255) / 256, 256, 0, stream>>>(
        W1, W2, Wg1, Wg2, b1, b2, Wc_t, Wg1t, Wg2t, hbuf);

    // CSR build: deg -> offsets -> bucketed multi-split -> LDS placement
    hipMemsetAsync(deg, 0, (size_t)NN * sizeof(int), stream);
    count_kernel<<<(EE + 255) / 256, 256, 0, stream>>>(dst, deg);
    scan_partial_kernel<<<NB, SCAN_B, 0, stream>>>(deg, parts);
    scan_base_kernel<<<1, 128, 0, stream>>>(parts, offs);
    scan_apply_kernel<<<NB, SCAN_B, 0, stream>>>(deg, parts, offs, curs);
    binit_kernel<<<(NBKA + 255) / 256, 256, 0, stream>>>(offs, gcur);
    bucket_kernel<<<(EE + CHK - 1) / CHK, 256, 0, stream>>>(src, dst, gcur, ebuf);
    csr_place_kernel<<<NBUK, 256, 0, stream>>>(ebuf, offs, curs, csr);

    // Pipeline
    gemm1_mfma<<<(NN + 127) / 128, 256, 0, stream>>>(x1, x2, Wc_t, Wg1t, hbuf, z_h);
    gather1_kernel<<<(NN + 3) / 4, 256, 0, stream>>>(z_h, offs, csr, agg);
    gemm2_mfma<<<(NN + 127) / 128, 256, 0, stream>>>(agg, Wg2t, bg1, gamma, beta,
                                                     rmean, rvar, z2_h);
    gather2_kernel<<<(NN + 3) / 4, 256, 0, stream>>>(z2_h, offs, csr, bg2, out);
}

// Round 3
// 638.363 us; speedup vs baseline: 1.0780x; 1.0044x over previous
//
#include <hip/hip_runtime.h>
#include <hip/hip_fp16.h>
#include <cstddef>

#define NN    100000
#define EE    1600000
#define F1D   512
#define F3D   128
#define HD    128
#define CD    64
#define SWc   0.2f
#define FWc   0.8f
#define BN_EPS 1e-5f

#define SCAN_B 1024
#define NB ((NN + SCAN_B - 1) / SCAN_B)   // 98

// Bucketed CSR build params
#define BSH   7                            // bucket = dst >> 7 (128 nodes/bucket)
#define NBKA  1024                         // bucket array size (782 used)
#define NBUK  ((NN + 127) / 128)           // 782
#define CHK   4096                         // edges per multi-split chunk
#define BCAP  8192                         // LDS staging capacity per bucket

// gemm1 dynamic-LDS layout: phase1 As[128][72]+Bs[128][72] = 36864 B;
// phase2 Hs[128][136] (overlays As+Bs) + Bs2[128][72] at 34816 = 53248 B total.
#define G1_LDS 53248

typedef _Float16 half8 __attribute__((ext_vector_type(8)));
typedef float f32x4 __attribute__((ext_vector_type(4)));

// ===========================================================================
// CSR build: deg-count -> 3-phase multi-block scan -> bucketed placement
// ===========================================================================
__global__ __launch_bounds__(256) void count_kernel(
    const int* __restrict__ dst, int* __restrict__ deg)
{
    int e = blockIdx.x * 256 + threadIdx.x;
    if (e < EE) atomicAdd(&deg[dst[e]], 1);
}

// Phase A: per-block reduce of deg -> partials[NB]
__global__ __launch_bounds__(SCAN_B) void scan_partial_kernel(
    const int* __restrict__ deg, int* __restrict__ partials)
{
    __shared__ int sh[SCAN_B / 64];
    int i = blockIdx.x * SCAN_B + threadIdx.x;
    int v = (i < NN) ? deg[i] : 0;
#pragma unroll
    for (int d = 32; d > 0; d >>= 1) v += __shfl_down(v, d, 64);
    int lane = threadIdx.x & 63, wv = threadIdx.x >> 6;
    if (lane == 0) sh[wv] = v;
    __syncthreads();
    if (threadIdx.x < SCAN_B / 64) {
        int s = sh[threadIdx.x];
#pragma unroll
        for (int d = SCAN_B / 128; d > 0; d >>= 1) s += __shfl_down(s, d, 64);
        if (threadIdx.x == 0) partials[blockIdx.x] = s;
    }
}

// Phase B: 1 small block exclusive-scans partials in place; writes offsets[NN]
__global__ __launch_bounds__(128) void scan_base_kernel(
    int* __restrict__ partials, int* __restrict__ offsets)
{
    __shared__ int sh[128];
    int t = threadIdx.x;
    int v = (t < NB) ? partials[t] : 0;
    sh[t] = v;
    __syncthreads();
    for (int d = 1; d < 128; d <<= 1) {
        int u = (t >= d) ? sh[t - d] : 0;
        __syncthreads();
        sh[t] += u;
        __syncthreads();
    }
    if (t < NB) partials[t] = sh[t] - v;           // exclusive base per block
    if (t == NB - 1) offsets[NN] = sh[t];          // total == EE
}

// Phase C: per-block Hillis-Steele scan + base -> offsets & cursor
__global__ __launch_bounds__(SCAN_B) void scan_apply_kernel(
    const int* __restrict__ deg, const int* __restrict__ partials,
    int* __restrict__ offsets, int* __restrict__ cursor)
{
    __shared__ int sh[SCAN_B];
    int t = threadIdx.x;
    int i = blockIdx.x * SCAN_B + t;
    int v = (i < NN) ? deg[i] : 0;
    sh[t] = v;
    __syncthreads();
    for (int d = 1; d < SCAN_B; d <<= 1) {
        int u = (t >= d) ? sh[t - d] : 0;
        __syncthreads();
        sh[t] += u;
        __syncthreads();
    }
    if (i < NN) {
        int excl = sh[t] - v + partials[blockIdx.x];
        offsets[i] = excl;
        cursor[i]  = excl;
    }
}

// Init bucket cursors: gcur[b] = offsets[min(b*128, NN)]
__global__ __launch_bounds__(256) void binit_kernel(
    const int* __restrict__ offsets, int* __restrict__ gcur)
{
    int b = blockIdx.x * 256 + threadIdx.x;
    if (b < NBKA) {
        int n = b << BSH;
        if (n > NN) n = NN;
        gcur[b] = offsets[n];
    }
}

// Multi-split: chunk -> LDS histogram by bucket -> scan -> global reserve ->
// LDS reorder -> coalesced run writes into ebuf. ebuf region for bucket b is
// exactly [offsets[b*128], offsets[(b+1)*128]) since gcur starts there and
// total per-bucket count == sum of degs in its node range.
__global__ __launch_bounds__(256) void bucket_kernel(
    const int* __restrict__ src, const int* __restrict__ dst,
    int* __restrict__ gcur, int* __restrict__ ebuf)
{
    __shared__ int hist[NBKA];     // counts -> exclusive offsets -> cursor
    __shared__ int gb2[NBKA];      // global_base - local_offset
    __shared__ int tsum[256];
    __shared__ int stage[CHK];     // packed (src<<7)|dlocal, bucket-ordered
    __shared__ int destg[CHK];     // global destination index in ebuf

    const int t  = threadIdx.x;
    const int e0 = blockIdx.x * CHK;
    int ecnt = EE - e0;
    if (ecnt > CHK) ecnt = CHK;

    for (int b = t; b < NBKA; b += 256) hist[b] = 0;
    __syncthreads();

    // pass 1: histogram
    for (int i = t; i < ecnt; i += 256) {
        int d = dst[e0 + i];
        atomicAdd(&hist[d >> BSH], 1);
    }
    __syncthreads();

    // exclusive scan of 1024 counts (thread t owns buckets 4t..4t+3)
    int a0 = hist[4 * t], a1 = hist[4 * t + 1];
    int a2 = hist[4 * t + 2], a3 = hist[4 * t + 3];
    int tot = a0 + a1 + a2 + a3;
    tsum[t] = tot;
    __syncthreads();
    for (int d = 1; d < 256; d <<= 1) {
        int u = (t >= d) ? tsum[t - d] : 0;
        __syncthreads();
        tsum[t] += u;
        __syncthreads();
    }
    int base = tsum[t] - tot;
    int o0 = base, o1 = base + a0, o2 = base + a0 + a1, o3 = base + a0 + a1 + a2;
    // reserve global runs (one atomic per non-empty (block,bucket))
    if (a0 > 0) gb2[4 * t]     = atomicAdd(&gcur[4 * t],     a0) - o0;
    if (a1 > 0) gb2[4 * t + 1] = atomicAdd(&gcur[4 * t + 1], a1) - o1;
    if (a2 > 0) gb2[4 * t + 2] = atomicAdd(&gcur[4 * t + 2], a2) - o2;
    if (a3 > 0) gb2[4 * t + 3] = atomicAdd(&gcur[4 * t + 3], a3) - o3;
    hist[4 * t] = o0; hist[4 * t + 1] = o1;
    hist[4 * t + 2] = o2; hist[4 * t + 3] = o3;
    __syncthreads();

    // pass 2: re-read edges, place into LDS staging ordered by bucket
    for (int i = t; i < ecnt; i += 256) {
        int d = dst[e0 + i];
        int s = src[e0 + i];
        int b = d >> BSH;
        int pos = atomicAdd(&hist[b], 1);
        stage[pos] = (s << BSH) | (d & 127);
        destg[pos] = gb2[b] + pos;
    }
    __syncthreads();

    // pass 3: coalesced copy-out (consecutive slots -> consecutive dest in runs)
    for (int sx = t; sx < ecnt; sx += 256) ebuf[destg[sx]] = stage[sx];
}

// Per-bucket placement: scatter inside LDS via per-node cursors, then one
// contiguous coalesced dump into csr. Fallback to global-cursor scatter for
// (practically nonexistent) buckets larger than BCAP.
__global__ __launch_bounds__(256) void csr_place_kernel(
    const int* __restrict__ ebuf, const int* __restrict__ offsets,
    int* __restrict__ cursor, int* __restrict__ csr)
{
    __shared__ int lcur[128];
    __shared__ int stage[BCAP];

    const int b   = blockIdx.x;
    const int t   = threadIdx.x;
    const int nb0 = b << BSH;
    int nb1 = nb0 + 128;
    if (nb1 > NN) nb1 = NN;
    const int rbeg = offsets[nb0];
    const int rend = offsets[nb1];
    const int L = rend - rbeg;

    if (L <= BCAP) {
        if (t < nb1 - nb0) lcur[t] = offsets[nb0 + t] - rbeg;
        __syncthreads();
        for (int e = rbeg + t; e < rend; e += 256) {
            int p = ebuf[e];
            int pos = atomicAdd(&lcur[p & 127], 1);
            stage[pos] = p >> BSH;
        }
        __syncthreads();
        for (int s = t; s < L; s += 256) csr[rbeg + s] = stage[s];
    } else {
        for (int e = rbeg + t; e < rend; e += 256) {
            int p = ebuf[e];
            int node = nb0 + (p & 127);
            int pos = atomicAdd(&cursor[node], 1);
            csr[pos] = p >> BSH;
        }
    }
}

// ===========================================================================
// Prep: Wc_t[n=128][k=640] = f16(FW*W1^T | SW*W2^T); Wg1_t[n=128][k=128];
//       Wg2_t[n=64][k=128]; hbuf[128] = FW*b1 + SW*b2
// ===========================================================================
__global__ __launch_bounds__(256) void prep_kernel(
    const float* __restrict__ W1, const float* __restrict__ W2,
    const float* __restrict__ Wg1, const float* __restrict__ Wg2,
    const float* __restrict__ b1, const float* __restrict__ b2,
    _Float16* __restrict__ Wc_t, _Float16* __restrict__ Wg1_t,
    _Float16* __restrict__ Wg2_t, float* __restrict__ hbuf)
{
    int i = blockIdx.x * 256 + threadIdx.x;
    if (i < 128 * 640) {
        int n = i / 640, k = i % 640;
        float v = (k < F1D) ? FWc * W1[(size_t)k * HD + n]
                            : SWc * W2[(size_t)(k - F1D) * HD + n];
        Wc_t[i] = (_Float16)v;
    } else if (i < 128 * 640 + 128 * 128) {
        int j = i - 128 * 640; int n = j / 128, k = j % 128;
        Wg1_t[j] = (_Float16)Wg1[(size_t)k * HD + n];
    } else if (i < 128 * 640 + 128 * 128 + 64 * 128) {
        int j = i - 128 * 640 - 128 * 128; int n = j / 128, k = j % 128;
        Wg2_t[j] = (_Float16)Wg2[(size_t)k * CD + n];
    } else if (i < 128 * 640 + 128 * 128 + 64 * 128 + 128) {
        int j = i - (128 * 640 + 128 * 128 + 64 * 128);
        hbuf[j] = FWc * b1[j] + SWc * b2[j];
    }
}

// ===========================================================================
// GEMM1 (MFMA f16): h = [x1|x2] @ Wc + hb;  z = h @ Wg1   (z f16)
// Block 256 = 4 waves. Tile M=128, N=128, K=640 (BK=64). Wave: 32 rows x 128.
// v3: dynamic-LDS overlay (53248 B -> 3 blocks/CU) + register prefetch of the
// next K-tile issued between the write barrier and the MFMA, so the implicit
// vmcnt(0) drain at the loop-end __syncthreads lands AFTER the MFMA (latency
// hidden under compute instead of exposed at cvt time).
// ===========================================================================
__global__ __launch_bounds__(256, 3) void gemm1_mfma(
    const float* __restrict__ x1, const float* __restrict__ x2,
    const _Float16* __restrict__ Wc_t, const _Float16* __restrict__ Wg1_t,
    const float* __restrict__ hbuf, _Float16* __restrict__ z)
{
    extern __shared__ char pool[];
    _Float16 (*As)[72]  = (_Float16(*)[72])pool;               // phase 1
    _Float16 (*Bs)[72]  = (_Float16(*)[72])(pool + 18432);     // phase 1
    _Float16 (*Hs)[136] = (_Float16(*)[136])pool;              // phase 2 (overlay)
    _Float16 (*Bs2)[72] = (_Float16(*)[72])(pool + 34816);     // phase 2 W staging

    const int tid  = threadIdx.x;
    const int wave = tid >> 6;
    const int lane = tid & 63;
    const int quad = lane >> 4;
    const int l16  = lane & 15;
    const int row0 = blockIdx.x * 128;

    const int sr = tid >> 1;           // staging row 0..127
    const int sc = (tid & 1) * 32;     // staging col offset
    const int gr = row0 + sr;
    const bool valid = gr < NN;

    f32x4 acc[2][8];
    const f32x4 zero4 = {0.f, 0.f, 0.f, 0.f};
#pragma unroll
    for (int mi = 0; mi < 2; ++mi)
#pragma unroll
        for (int ni = 0; ni < 8; ++ni) acc[mi][ni] = zero4;

    // register staging for the next K-tile
    float4 xr[8];
    half8  wr[4];

    // ---- prologue: load tile 0 into regs ----
    {
        if (valid) {
            const float4* rp = (const float4*)(x1 + (size_t)gr * F1D + sc);
#pragma unroll
            for (int i = 0; i < 8; ++i) xr[i] = rp[i];
        }
        const _Float16* wp = Wc_t + (size_t)sr * 640 + sc;
#pragma unroll
        for (int i = 0; i < 4; ++i) wr[i] = *(const half8*)(wp + i * 8);
    }

    // ---- Phase 1: h = X @ Wc over K=640 in 10 tiles of 64 ----
    for (int t = 0; t < 10; ++t) {
        // convert + LDS-write current tile from regs
        if (valid) {
#pragma unroll
            for (int i = 0; i < 4; ++i) {
                float4 f0 = xr[2 * i];
                float4 f1 = xr[2 * i + 1];
                half8 hv = { (_Float16)f0.x, (_Float16)f0.y, (_Float16)f0.z, (_Float16)f0.w,
                             (_Float16)f1.x, (_Float16)f1.y, (_Float16)f1.z, (_Float16)f1.w };
                *(half8*)&As[sr][sc + i * 8] = hv;
            }
        } else {
            half8 zv = { (_Float16)0.f, (_Float16)0.f, (_Float16)0.f, (_Float16)0.f,
                         (_Float16)0.f, (_Float16)0.f, (_Float16)0.f, (_Float16)0.f };
#pragma unroll
            for (int i = 0; i < 4; ++i) *(half8*)&As[sr][sc + i * 8] = zv;
        }
#pragma unroll
        for (int i = 0; i < 4; ++i)
            *(half8*)&Bs[sr][sc + i * 8] = wr[i];

        __syncthreads();   // writes visible (nothing in flight to drain)

        // prefetch tile t+1 into regs — in flight during the MFMA below
        if (t + 1 < 10) {
            const float* xp; int stride, kb;
            if (t + 1 < 8) { xp = x1; stride = F1D; kb = (t + 1) * 64; }
            else           { xp = x2; stride = F3D; kb = (t + 1 - 8) * 64; }
            if (valid) {
                const float4* rp = (const float4*)(xp + (size_t)gr * stride + kb + sc);
#pragma unroll
                for (int i = 0; i < 8; ++i) xr[i] = rp[i];
            }
            const _Float16* wp = Wc_t + (size_t)sr * 640 + (t + 1) * 64 + sc;
#pragma unroll
            for (int i = 0; i < 4; ++i) wr[i] = *(const half8*)(wp + i * 8);
        }

#pragma unroll
        for (int ks = 0; ks < 2; ++ks) {
            half8 a[2], b[8];
#pragma unroll
            for (int mi = 0; mi < 2; ++mi)
                a[mi] = *(const half8*)&As[wave * 32 + mi * 16 + l16][ks * 32 + quad * 8];
#pragma unroll
            for (int ni = 0; ni < 8; ++ni)
                b[ni] = *(const half8*)&Bs[ni * 16 + l16][ks * 32 + quad * 8];
#pragma unroll
            for (int mi = 0; mi < 2; ++mi)
#pragma unroll
                for (int ni = 0; ni < 8; ++ni)
                    acc[mi][ni] = __builtin_amdgcn_mfma_f32_16x16x32_f16(
                        a[mi], b[ni], acc[mi][ni], 0, 0, 0);
        }
        __syncthreads();   // all reads done; drains the t+1 prefetch (post-MFMA)
    }

    // ---- h + bias -> Hs (f16, overlays As+Bs). C-layout: col=l16, row=quad*4+r.
    //      Safe: loop-end sync guarantees all As/Bs reads complete. ----
    {
        float hbv[8];
#pragma unroll
        for (int ni = 0; ni < 8; ++ni) hbv[ni] = hbuf[ni * 16 + l16];
#pragma unroll
        for (int mi = 0; mi < 2; ++mi)
#pragma unroll
            for (int ni = 0; ni < 8; ++ni)
#pragma unroll
                for (int r = 0; r < 4; ++r)
                    Hs[wave * 32 + mi * 16 + quad * 4 + r][ni * 16 + l16] =
                        (_Float16)(acc[mi][ni][r] + hbv[ni]);
    }

    // ---- Phase 2: z = h @ Wg1, K=128 in 2 tiles of 64 (Bs2 staging) ----
#pragma unroll
    for (int mi = 0; mi < 2; ++mi)
#pragma unroll
        for (int ni = 0; ni < 8; ++ni) acc[mi][ni] = zero4;

    for (int t = 0; t < 2; ++t) {
        __syncthreads();
        {
            const _Float16* wp = Wg1_t + (size_t)sr * 128 + t * 64 + sc;
#pragma unroll
            for (int i = 0; i < 4; ++i)
                *(half8*)&Bs2[sr][sc + i * 8] = *(const half8*)(wp + i * 8);
        }
        __syncthreads();
#pragma unroll
        for (int ks = 0; ks < 2; ++ks) {
            half8 a[2], b[8];
#pragma unroll
            for (int mi = 0; mi < 2; ++mi)
                a[mi] = *(const half8*)&Hs[wave * 32 + mi * 16 + l16][t * 64 + ks * 32 + quad * 8];
#pragma unroll
            for (int ni = 0; ni < 8; ++ni)
                b[ni] = *(const half8*)&Bs2[ni * 16 + l16][ks * 32 + quad * 8];
#pragma unroll
            for (int mi = 0; mi < 2; ++mi)
#pragma unroll
                for (int ni = 0; ni < 8; ++ni)
                    acc[mi][ni] = __builtin_amdgcn_mfma_f32_16x16x32_f16(
                        a[mi], b[ni], acc[mi][ni], 0, 0, 0);
        }
    }

    // ---- z tile -> Hs (overwrite, wave-own rows), then coalesced store ----
#pragma unroll
    for (int mi = 0; mi < 2; ++mi)
#pragma unroll
        for (int ni = 0; ni < 8; ++ni)
#pragma unroll
            for (int r = 0; r < 4; ++r)
                Hs[wave * 32 + mi * 16 + quad * 4 + r][ni * 16 + l16] =
                    (_Float16)acc[mi][ni][r];
    __syncthreads();
    {
        if (valid) {
            int c0 = (tid & 1) * 64;
            _Float16* zp = z + (size_t)gr * HD + c0;
#pragma unroll
            for (int i = 0; i < 8; ++i)
                *(half8*)(zp + i * 8) = *(const half8*)&Hs[sr][c0 + i * 8];
        }
    }
}

// ===========================================================================
// GEMM2 (MFMA f16, fused BN+ReLU): z2 = relu(agg*s + t) @ Wg2   (z2 f16)
// ===========================================================================
__global__ __launch_bounds__(256) void gemm2_mfma(
    const float* __restrict__ agg, const _Float16* __restrict__ Wg2_t,
    const float* __restrict__ bg1, const float* __restrict__ gamma,
    const float* __restrict__ beta, const float* __restrict__ rmean,
    const float* __restrict__ rvar, _Float16* __restrict__ z2)
{
    __shared__ __align__(16) _Float16 As[128][72];
    __shared__ __align__(16) _Float16 Bs[64][72];
    __shared__ float sS[HD], sT[HD];

    const int tid = threadIdx.x;
    if (tid < HD) {
        float s = gamma[tid] * rsqrtf(rvar[tid] + BN_EPS);
        sS[tid] = s;
        sT[tid] = (bg1[tid] - rmean[tid]) * s + beta[tid];
    }
    __syncthreads();

    const int wave = tid >> 6;
    const int lane = tid & 63;
    const int quad = lane >> 4;
    const int l16  = lane & 15;
    const int row0 = blockIdx.x * 128;
    const int sr = tid >> 1;
    const int sc = (tid & 1) * 32;

    f32x4 acc[2][4];
    const f32x4 zero4 = {0.f, 0.f, 0.f, 0.f};
#pragma unroll
    for (int mi = 0; mi < 2; ++mi)
#pragma unroll
        for (int ni = 0; ni < 4; ++ni) acc[mi][ni] = zero4;

    for (int t = 0; t < 2; ++t) {
        __syncthreads();
        {
            int gr = row0 + sr;
            if (gr < NN) {
                const float4* rp = (const float4*)(agg + (size_t)gr * HD + t * 64 + sc);
#pragma unroll
                for (int i = 0; i < 4; ++i) {
                    float4 f0 = rp[2 * i];
                    float4 f1 = rp[2 * i + 1];
                    int k = t * 64 + sc + i * 8;
                    float v0 = fmaxf(fmaf(f0.x, sS[k + 0], sT[k + 0]), 0.f);
                    float v1 = fmaxf(fmaf(f0.y, sS[k + 1], sT[k + 1]), 0.f);
                    float v2 = fmaxf(fmaf(f0.z, sS[k + 2], sT[k + 2]), 0.f);
                    float v3 = fmaxf(fmaf(f0.w, sS[k + 3], sT[k + 3]), 0.f);
                    float v4 = fmaxf(fmaf(f1.x, sS[k + 4], sT[k + 4]), 0.f);
                    float v5 = fmaxf(fmaf(f1.y, sS[k + 5], sT[k + 5]), 0.f);
                    float v6 = fmaxf(fmaf(f1.z, sS[k + 6], sT[k + 6]), 0.f);
                    float v7 = fmaxf(fmaf(f1.w, sS[k + 7], sT[k + 7]), 0.f);
                    half8 hv = { (_Float16)v0, (_Float16)v1, (_Float16)v2, (_Float16)v3,
                                 (_Float16)v4, (_Float16)v5, (_Float16)v6, (_Float16)v7 };
                    *(half8*)&As[sr][sc + i * 8] = hv;
                }
            } else {
                half8 zv = { (_Float16)0.f, (_Float16)0.f, (_Float16)0.f, (_Float16)0.f,
                             (_Float16)0.f, (_Float16)0.f, (_Float16)0.f, (_Float16)0.f };
#pragma unroll
                for (int i = 0; i < 4; ++i) *(half8*)&As[sr][sc + i * 8] = zv;
            }
            int n = tid >> 2, c = (tid & 3) * 16;
            const _Float16* wp = Wg2_t + (size_t)n * 128 + t * 64 + c;
            *(half8*)&Bs[n][c]     = *(const half8*)wp;
            *(half8*)&Bs[n][c + 8] = *(const half8*)(wp + 8);
        }
        __syncthreads();
#pragma unroll
        for (int ks = 0; ks < 2; ++ks) {
            half8 a[2], b[4];
#pragma unroll
            for (int mi = 0; mi < 2; ++mi)
                a[mi] = *(const half8*)&As[wave * 32 + mi * 16 + l16][ks * 32 + quad * 8];
#pragma unroll
            for (int ni = 0; ni < 4; ++ni)
                b[ni] = *(const half8*)&Bs[ni * 16 + l16][ks * 32 + quad * 8];
#pragma unroll
            for (int mi = 0; mi < 2; ++mi)
#pragma unroll
                for (int ni = 0; ni < 4; ++ni)
                    acc[mi][ni] = __builtin_amdgcn_mfma_f32_16x16x32_f16(
                        a[mi], b[ni], acc[mi][ni], 0, 0, 0);
        }
    }

    __syncthreads();
    // z2 tile -> As reuse (wave-own rows), then coalesced store
#pragma unroll
    for (int mi = 0; mi < 2; ++mi)
#pragma unroll
        for (int ni = 0; ni < 4; ++ni)
#pragma unroll
            for (int r = 0; r < 4; ++r)
                As[wave * 32 + mi * 16 + quad * 4 + r][ni * 16 + l16] =
                    (_Float16)acc[mi][ni][r];
    __syncthreads();
    {
        int gr = row0 + sr;
        if (gr < NN) {
            _Float16* zp = z2 + (size_t)gr * CD + sc;
            *(half8*)(zp)      = *(const half8*)&As[sr][sc];
            *(half8*)(zp + 8)  = *(const half8*)&As[sr][sc + 8];
            *(half8*)(zp + 16) = *(const half8*)&As[sr][sc + 16];
            *(half8*)(zp + 24) = *(const half8*)&As[sr][sc + 24];
        }
    }
}

// ===========================================================================
// Gather 1: agg[n] = sum_{e in CSR[n]} z[src[e]]  — 1 wave/node, 4 edges per
// load instruction (h = lane>>4 edge slot, fl = lane&15 -> 16B feature slice),
// 64 indices prefetched per chunk, #pragma unroll 4 => up to 16 edges in
// flight per wave.
// ===========================================================================
__global__ __launch_bounds__(256) void gather1_kernel(
    const _Float16* __restrict__ z, const int* __restrict__ offsets,
    const int* __restrict__ csr_src, float* __restrict__ agg)
{
    int node = blockIdx.x * 4 + (threadIdx.x >> 6);
    if (node >= NN) return;
    const int lane = threadIdx.x & 63;
    const int h  = lane >> 4;      // edge slot within quad
    const int fl = lane & 15;      // halves fl*8 .. fl*8+7 (16 B)

    int beg = offsets[node];
    int cnt = offsets[node + 1] - beg;

    float a0 = 0.f, a1 = 0.f, a2 = 0.f, a3 = 0.f;
    float a4 = 0.f, a5 = 0.f, a6 = 0.f, a7 = 0.f;

    for (int j0 = 0; j0 < cnt; j0 += 64) {
        int cntc = cnt - j0; if (cntc > 64) cntc = 64;
        int myidx = (lane < cntc) ? csr_src[beg + j0 + lane] : 0;
        int nq = (cntc + 3) >> 2;
#pragma unroll 4
        for (int i = 0; i < nq; ++i) {
            int e = i * 4 + h;
            int si = __shfl(myidx, e);
            float m = (e < cntc) ? 1.f : 0.f;
            float4 raw = *(const float4*)(z + (size_t)si * HD + fl * 8);
            const __half2* hp = (const __half2*)&raw;
            float2 f0 = __half22float2(hp[0]);
            float2 f1 = __half22float2(hp[1]);
            float2 f2 = __half22float2(hp[2]);
            float2 f3 = __half22float2(hp[3]);
            a0 = fmaf(m, f0.x, a0); a1 = fmaf(m, f0.y, a1);
            a2 = fmaf(m, f1.x, a2); a3 = fmaf(m, f1.y, a3);
            a4 = fmaf(m, f2.x, a4); a5 = fmaf(m, f2.y, a5);
            a6 = fmaf(m, f3.x, a6); a7 = fmaf(m, f3.y, a7);
        }
    }

    // reduce the 4 edge slots (lanes l, l^16, l^32, l^48)
    a0 += __shfl_xor(a0, 16); a1 += __shfl_xor(a1, 16);
    a2 += __shfl_xor(a2, 16); a3 += __shfl_xor(a3, 16);
    a4 += __shfl_xor(a4, 16); a5 += __shfl_xor(a5, 16);
    a6 += __shfl_xor(a6, 16); a7 += __shfl_xor(a7, 16);
    a0 += __shfl_xor(a0, 32); a1 += __shfl_xor(a1, 32);
    a2 += __shfl_xor(a2, 32); a3 += __shfl_xor(a3, 32);
    a4 += __shfl_xor(a4, 32); a5 += __shfl_xor(a5, 32);
    a6 += __shfl_xor(a6, 32); a7 += __shfl_xor(a7, 32);

    if (h == 0) {
        float* op = agg + (size_t)node * HD + fl * 8;
        float4 o0 = make_float4(a0, a1, a2, a3);
        float4 o1 = make_float4(a4, a5, a6, a7);
        *(float4*)op       = o0;
        *(float4*)(op + 4) = o1;
    }
}

// ===========================================================================
// Gather 2: out[n] = bg2 + sum_{e in CSR[n]} z2[src[e]] — same structure,
// 8 B feature slice per lane (row = 64 halves).
// ===========================================================================
__global__ __launch_bounds__(256) void gather2_kernel(
    const _Float16* __restrict__ z2, const int* __restrict__ offsets,
    const int* __restrict__ csr_src, const float* __restrict__ bg2,
    float* __restrict__ out)
{
    int node = blockIdx.x * 4 + (threadIdx.x >> 6);
    if (node >= NN) return;
    const int lane = threadIdx.x & 63;
    const int h  = lane >> 4;      // edge slot within quad
    const int fl = lane & 15;      // halves fl*4 .. fl*4+3 (8 B)

    int beg = offsets[node];
    int cnt = offsets[node + 1] - beg;

    float a0 = 0.f, a1 = 0.f, a2 = 0.f, a3 = 0.f;

    for (int j0 = 0; j0 < cnt; j0 += 64) {
        int cntc = cnt - j0; if (cntc > 64) cntc = 64;
        int myidx = (lane < cntc) ? csr_src[beg + j0 + lane] : 0;
        int nq = (cntc + 3) >> 2;
#pragma unroll 4
        for (int i = 0; i < nq; ++i) {
            int e = i * 4 + h;
            int si = __shfl(myidx, e);
            float m = (e < cntc) ? 1.f : 0.f;
            float2 raw = *(const float2*)(z2 + (size_t)si * CD + fl * 4);
            const __half2* hp = (const __half2*)&raw;
            float2 f0 = __half22float2(hp[0]);
            float2 f1 = __half22float2(hp[1]);
            a0 = fmaf(m, f0.x, a0); a1 = fmaf(m, f0.y, a1);
            a2 = fmaf(m, f1.x, a2); a3 = fmaf(m, f1.y, a3);
        }
    }

    a0 += __shfl_xor(a0, 16); a1 += __shfl_xor(a1, 16);
    a2 += __shfl_xor(a2, 16); a3 += __shfl_xor(a3, 16);
    a0 += __shfl_xor(a0, 32); a1 += __shfl_xor(a1, 32);
    a2 += __shfl_xor(a2, 32); a3 += __shfl_xor(a3, 32);

    if (h == 0) {
        float4 bv = *(const float4*)(bg2 + fl * 4);
        float4 o = make_float4(a0 + bv.x, a1 + bv.y, a2 + bv.z, a3 + bv.w);
        *(float4*)(out + (size_t)node * CD + fl * 4) = o;
    }
}

// ===========================================================================
extern "C" void kernel_launch(void* const* d_in, const int* in_sizes, int n_in,
                              void* d_out, int out_size, void* d_ws, size_t ws_size,
                              hipStream_t stream)
{
    const float* x1    = (const float*)d_in[0];
    const float* x2    = (const float*)d_in[1];
    const int*   ei    = (const int*)d_in[2];
    const float* W1    = (const float*)d_in[3];
    const float* b1    = (const float*)d_in[4];
    const float* W2    = (const float*)d_in[5];
    const float* b2    = (const float*)d_in[6];
    const float* Wg1   = (const float*)d_in[7];
    const float* bg1   = (const float*)d_in[8];
    const float* Wg2   = (const float*)d_in[9];
    const float* bg2   = (const float*)d_in[10];
    const float* gamma = (const float*)d_in[11];
    const float* beta  = (const float*)d_in[12];
    const float* rmean = (const float*)d_in[13];
    const float* rvar  = (const float*)d_in[14];
    float* out = (float*)d_out;

    // ---- workspace layout (all chunks 16B-aligned), ~85 MB ----
    char* p = (char*)d_ws;
    _Float16* z_h  = (_Float16*)p; p += (size_t)NN * HD * sizeof(_Float16);   // 25.6 MB
    float*  agg    = (float*)p;    p += (size_t)NN * HD * sizeof(float);      // 51.2 MB
    int*    csr    = (int*)p;      p += (size_t)EE * sizeof(int);             // 6.4 MB
    int*    offs   = (int*)p;      p += (size_t)(NN + 16) * sizeof(int);
    int*    curs   = (int*)p;      p += (size_t)(NN + 16) * sizeof(int);
    int*    deg    = (int*)p;      p += (size_t)(NN + 16) * sizeof(int);
    int*    parts  = (int*)p;      p += (size_t)(NB + 16) * sizeof(int);
    int*    gcur   = (int*)p;      p += (size_t)(NBKA + 16) * sizeof(int);    // 4 KB
    _Float16* Wc_t = (_Float16*)p; p += (size_t)128 * 640 * sizeof(_Float16); // 160 KB
    _Float16* Wg1t = (_Float16*)p; p += (size_t)128 * 128 * sizeof(_Float16);
    _Float16* Wg2t = (_Float16*)p; p += (size_t)64 * 128 * sizeof(_Float16);
    float*  hbuf   = (float*)p;    p += 128 * sizeof(float);
    _Float16* z2_h = z_h;          // overlay: z dead after gather1
    int*    ebuf   = (int*)agg;    // overlay: agg written only after csr_place

    const int* src = ei;
    const int* dst = ei + EE;

    // Weight prep (f16, transposed, scales folded)
    prep_kernel<<<(128 * 640 + 128 * 128 + 64 * 128 + 128 + 255) / 256, 256, 0, stream>>>(
        W1, W2, Wg1, Wg2, b1, b2, Wc_t, Wg1t, Wg2t, hbuf);

    // CSR build: deg -> offsets -> bucketed multi-split -> LDS placement
    hipMemsetAsync(deg, 0, (size_t)NN * sizeof(int), stream);
    count_kernel<<<(EE + 255) / 256, 256, 0, stream>>>(dst, deg);
    scan_partial_kernel<<<NB, SCAN_B, 0, stream>>>(deg, parts);
    scan_base_kernel<<<1, 128, 0, stream>>>(parts, offs);
    scan_apply_kernel<<<NB, SCAN_B, 0, stream>>>(deg, parts, offs, curs);
    binit_kernel<<<(NBKA + 255) / 256, 256, 0, stream>>>(offs, gcur);
    bucket_kernel<<<(EE + CHK - 1) / CHK, 256, 0, stream>>>(src, dst, gcur, ebuf);
    csr_place_kernel<<<NBUK, 256, 0, stream>>>(ebuf, offs, curs, csr);

    // Pipeline
    gemm1_mfma<<<(NN + 127) / 128, 256, G1_LDS, stream>>>(x1, x2, Wc_t, Wg1t, hbuf, z_h);
    gather1_kernel<<<(NN + 3) / 4, 256, 0, stream>>>(z_h, offs, csr, agg);
    gemm2_mfma<<<(NN + 127) / 128, 256, 0, stream>>>(agg, Wg2t, bg1, gamma, beta,
                                                     rmean, rvar, z2_h);
    gather2_kernel<<<(NN + 3) / 4, 256, 0, stream>>>(z2_h, offs, csr, bg2, out);
}